// Round 7
// baseline (1000.403 us; speedup 1.0000x reference)
//
#include <hip/hip_runtime.h>
#include <hip/hip_cooperative_groups.h>
#include <math.h>

namespace cg = cooperative_groups;

#define EPS 1e-5f

__device__ __forceinline__ float gelu_exact(float x) {
    return 0.5f * x * (1.0f + erff(x * 0.7071067811865476f));
}

// ---- threefry2x32-20 (JAX PRNG), partitionable scheme (verified round 1) ----
__device__ void threefry2x32(unsigned k0, unsigned k1, unsigned x0, unsigned x1,
                             unsigned& o0, unsigned& o1) {
    unsigned ks[3] = {k0, k1, k0 ^ k1 ^ 0x1BD11BDAu};
    const unsigned rot[2][4] = {{13u, 15u, 26u, 6u}, {17u, 29u, 16u, 24u}};
    x0 += ks[0]; x1 += ks[1];
#pragma unroll
    for (int i = 0; i < 5; i++) {
#pragma unroll
        for (int j = 0; j < 4; j++) {
            unsigned r = rot[i & 1][j];
            x0 += x1;
            x1 = (x1 << r) | (x1 >> (32 - r));
            x1 ^= x0;
        }
        x0 += ks[(i + 1) % 3];
        x1 += ks[(i + 2) % 3] + (unsigned)(i + 1);
    }
    o0 = x0; o1 = x1;
}

__device__ float gumbel_at(int j) {
    unsigned o0, o1;
    threefry2x32(0u, 42u, 0u, (unsigned)j, o0, o1);
    unsigned bits = o0 ^ o1;
    float f = __uint_as_float((bits >> 9) | 0x3F800000u) - 1.0f;  // [0,1)
    float u = fmaxf(f + 1.17549435e-38f, 1.17549435e-38f);
    return -logf(-logf(u));
}

struct MegaParams {
    const float *in_lt, *in_st;
    const float *Ws, *bs, *Wt, *bt;
    const float *Wh1, *bh1, *Wl1, *bl1, *Wh2, *bh2, *Wl2, *bl2;
    const float *Wh3, *bh3, *Wl3, *bl3, *Wr, *br, *proto;
    float* out;
    float *e_lt, *e_st, *O1T, *O2T, *O3T, *O4T, *O5T, *O6, *part, *sel_w;
    int* sel_r;
};

// ---- encode one (input,b,l) row per WAVE: no LDS, no barriers. ----
__device__ void encode_row_wave(int task, const MegaParams& p, int ln) {
    const float* x;
    float* e;
    int L, b, l;
    if (task < 16384) { x = p.in_lt; e = p.e_lt; L = 512; b = task >> 9; l = task & 511; }
    else { int u = task - 16384; x = p.in_st; e = p.e_st; L = 128; b = u >> 7; l = u & 127; }
    const float* xb = x + (size_t)b * L * 9;
    float seas_v = 0.f, mm_v = 0.f;
    if (ln < 9) {
        float x0 = xb[ln];
        float s = 0.f;
#pragma unroll
        for (int j = -12; j <= 12; j++) {
            int lj = l + j;
            lj = lj < 0 ? 0 : (lj >= L ? L - 1 : lj);
            s += xb[(size_t)lj * 9 + ln];
        }
        float mm = (s - 25.f * x0) * (1.0f / 25.0f);
        mm_v = mm;
        seas_v = (xb[(size_t)l * 9 + ln] - x0) - mm;
    }
    int h1 = ln, h2 = ln + 64;
    float ys1 = p.bs[h1], ys2 = p.bs[h2], yt1 = p.bt[h1], yt2 = p.bt[h2];
#pragma unroll
    for (int c = 0; c < 9; c++) {
        float sc = __shfl(seas_v, c, 64);
        float mc = __shfl(mm_v, c, 64);
        ys1 += sc * p.Ws[c * 128 + h1]; ys2 += sc * p.Ws[c * 128 + h2];
        yt1 += mc * p.Wt[c * 128 + h1]; yt2 += mc * p.Wt[c * 128 + h2];
    }
    float sa = ys1 + ys2, sb = yt1 + yt2;
#pragma unroll
    for (int off = 32; off > 0; off >>= 1) {
        sa += __shfl_xor(sa, off, 64);
        sb += __shfl_xor(sb, off, 64);
    }
    float ms = sa * (1.0f / 128.0f), mt = sb * (1.0f / 128.0f);
    float d1 = ys1 - ms, d2 = ys2 - ms, f1 = yt1 - mt, f2 = yt2 - mt;
    float qa = d1 * d1 + d2 * d2, qb = f1 * f1 + f2 * f2;
#pragma unroll
    for (int off = 32; off > 0; off >>= 1) {
        qa += __shfl_xor(qa, off, 64);
        qb += __shfl_xor(qb, off, 64);
    }
    float is = rsqrtf(qa * (1.0f / 128.0f) + EPS);
    float it = rsqrtf(qb * (1.0f / 128.0f) + EPS);
    float o1 = gelu_exact(d1 * is) + gelu_exact(f1 * it);
    float o2 = gelu_exact(d2 * is) + gelu_exact(f2 * it);
    float* eb = e + ((size_t)b * L + l) * 128;
    eb[h1] = o1;
    eb[h2] = o2;
}

// ---- wave-autonomous LBR layer phase (r6-proven body, tile-looped). ----
template <int K, int N, int WR, bool TRANS>
__device__ void layer_phase(float* lds,
                            const float* __restrict__ A, int S, int ABOFF,
                            const float* __restrict__ W, const float* __restrict__ bias,
                            float* __restrict__ out, int OROWS, int OBOFF,
                            int tilesX, int nB) {
    constexpr int CG = N / 4;
    constexpr int SG = 64 / CG;
    constexpr int RW = SG * WR;
    constexpr int MT = 4 * RW;
    constexpr int LOG2MT = (MT == 8) ? 3 : ((MT == 16) ? 4 : 5);
    const int t = threadIdx.x;
    const int w = t >> 6, ln = t & 63;
    const int sg = ln / CG;
    const int n0 = (ln % CG) * 4;
    const int ntask = tilesX * nB;
    for (int tt = blockIdx.x; tt < ntask; tt += gridDim.x) {
        const int bx = tt % tilesX, b = tt / tilesX;
        const int r0b = bx * MT;
        const int r0w = r0b + w * RW;
        float* As = lds + w * RW * K;
        const float* Ab = A + (size_t)b * ABOFF;
        for (int idx = ln; idx < RW * (K / 4); idx += 64) {
            int rr = idx / (K / 4), kk = idx % (K / 4);
            float4 v = *(const float4*)(Ab + (size_t)(r0w + rr) * S + kk * 4);
            *(float4*)(As + rr * K + kk * 4) = v;
        }
        float4 acc[WR];
        {
            float4 bv = *(const float4*)(bias + n0);
#pragma unroll
            for (int j = 0; j < WR; j++) acc[j] = bv;
        }
        const float* ap = As + (sg * WR) * K;
        const float* wp = W + n0;
#pragma unroll 2
        for (int k = 0; k < K; k += 4) {
            float4 w0 = *(const float4*)(wp);
            float4 w1 = *(const float4*)(wp + N);
            float4 w2 = *(const float4*)(wp + 2 * N);
            float4 w3 = *(const float4*)(wp + 3 * N);
            wp += 4 * N;
#pragma unroll
            for (int j = 0; j < WR; j++) {
                float4 a4 = *(const float4*)(ap + j * K + k);
                acc[j].x += a4.x * w0.x; acc[j].y += a4.x * w0.y;
                acc[j].z += a4.x * w0.z; acc[j].w += a4.x * w0.w;
                acc[j].x += a4.y * w1.x; acc[j].y += a4.y * w1.y;
                acc[j].z += a4.y * w1.z; acc[j].w += a4.y * w1.w;
                acc[j].x += a4.z * w2.x; acc[j].y += a4.z * w2.y;
                acc[j].z += a4.z * w2.z; acc[j].w += a4.z * w2.w;
                acc[j].x += a4.w * w3.x; acc[j].y += a4.w * w3.y;
                acc[j].z += a4.w * w3.z; acc[j].w += a4.w * w3.w;
            }
        }
        float4 res[WR];
#pragma unroll
        for (int j = 0; j < WR; j++) {
            float s = acc[j].x + acc[j].y + acc[j].z + acc[j].w;
#pragma unroll
            for (int off = CG / 2; off > 0; off >>= 1) s += __shfl_xor(s, off, 64);
            float m = s * (1.0f / (float)N);
            float dx = acc[j].x - m, dy = acc[j].y - m, dz = acc[j].z - m, dw = acc[j].w - m;
            float q = dx * dx + dy * dy + dz * dz + dw * dw;
#pragma unroll
            for (int off = CG / 2; off > 0; off >>= 1) q += __shfl_xor(q, off, 64);
            float inv = rsqrtf(q * (1.0f / (float)N) + EPS);
            res[j].x = gelu_exact(dx * inv);
            res[j].y = gelu_exact(dy * inv);
            res[j].z = gelu_exact(dz * inv);
            res[j].w = gelu_exact(dw * inv);
        }
        if constexpr (TRANS) {
            __syncthreads();
#pragma unroll
            for (int j = 0; j < WR; j++) {
                int rl = w * RW + sg * WR + j;
                *(float4*)(lds + rl * (N + 4) + n0) = res[j];
            }
            __syncthreads();
            float* ob = out + (size_t)b * OBOFF + r0b;
            for (int e2 = t; e2 < MT * N; e2 += 256) {
                int r = e2 & (MT - 1), n = e2 >> LOG2MT;
                ob[(size_t)n * OROWS + r] = lds[r * (N + 4) + n];
            }
            __syncthreads();  // protect lds before next iteration's staging
        } else {
            float* ob = out + (size_t)b * OBOFF;
#pragma unroll
            for (int j = 0; j < WR; j++) {
                int row = r0w + sg * WR + j;
                *(float4*)(ob + (size_t)row * N + n0) = res[j];
            }
        }
    }
}

// ---- the whole pipeline as one cooperative kernel ----
__global__ __launch_bounds__(256, 2) void mega(MegaParams p) {
    cg::grid_group grid = cg::this_grid();
    __shared__ float lds[8704];            // layers / logits O6-tile / einsum es
    __shared__ float red8[4][8];
    __shared__ int loc[32];
    __shared__ int s_gs;
    const int t = threadIdx.x;
    const int w = t >> 6, ln = t & 63;
    const int blk = blockIdx.x, nblk = gridDim.x;
    const int gw = blk * 4 + w;            // global wave id (4 waves/block)
    const int ngw = nblk * 4;

    // P0: encode (20480 row-tasks, one per wave)
    for (int task = gw; task < 20480; task += ngw) encode_row_wave(task, p, ln);
    grid.sync();
    // P1 h1: 16384 flat rows, MT=16 -> 1024 tiles
    layer_phase<128, 128, 2, true>(lds, p.e_lt, 128, 0, p.Wh1, p.bh1, p.O1T, 16384, 0, 1024, 1);
    grid.sync();
    // P2 l1: 128 rows/b, MT=8 -> 16 x 32
    layer_phase<512, 256, 2, true>(lds, p.O1T, 16384, 512, p.Wl1, p.bl1, p.O2T, 4096, 128, 16, 32);
    grid.sync();
    // P3 h2: 256 rows/b, MT=16 -> 16 x 32
    layer_phase<128, 128, 2, true>(lds, p.O2T, 4096, 128, p.Wh2, p.bh2, p.O3T, 8192, 256, 16, 32);
    grid.sync();
    // P4 l2: 128 rows/b, MT=8 -> 16 x 32
    layer_phase<256, 128, 1, true>(lds, p.O3T, 8192, 256, p.Wl2, p.bl2, p.O4T, 4096, 128, 16, 32);
    grid.sync();
    // P5 h3: 128 rows/b, MT=8 -> 16 x 32
    layer_phase<128, 128, 1, true>(lds, p.O4T, 4096, 128, p.Wh3, p.bh3, p.O5T, 4096, 128, 16, 32);
    grid.sync();
    // P6 l3: 128 rows/b, MT=16 -> 8 x 32, natural out O6[b][h][l4]
    layer_phase<128, 64, 1, false>(lds, p.O5T, 4096, 128, p.Wl3, p.bl3, p.O6, 0, 8192, 8, 32);
    grid.sync();

    // P7: logits + gumbel-softmax(hard) selection (32 tasks)
    for (int b = blk; b < 32; b += nblk) {
        const float4* ob4 = (const float4*)(p.O6 + (size_t)b * 8192);
        for (int i4 = t; i4 < 2048; i4 += 256) {
            float4 v = ob4[i4];
            int pidx = i4 * 4;
            int h = pidx >> 6, l4 = pidx & 63;
            *(float4*)(&lds[h * 68 + l4]) = v;
        }
        __syncthreads();
        float acc[8] = {0, 0, 0, 0, 0, 0, 0, 0};
#pragma unroll 4
        for (int q = 0; q < 32; q++) {
            int i = q * 256 + t;
            int l4 = i >> 7, h = i & 127;
            float v = lds[h * 68 + l4];
            const float4* wr = (const float4*)(p.Wr + (size_t)i * 8);
            float4 w0 = wr[0], w1 = wr[1];
            acc[0] += v * w0.x; acc[1] += v * w0.y; acc[2] += v * w0.z; acc[3] += v * w0.w;
            acc[4] += v * w1.x; acc[5] += v * w1.y; acc[6] += v * w1.z; acc[7] += v * w1.w;
        }
#pragma unroll
        for (int j = 0; j < 8; j++)
#pragma unroll
            for (int off = 32; off > 0; off >>= 1) acc[j] += __shfl_xor(acc[j], off, 64);
        if (ln == 0)
            for (int j = 0; j < 8; j++) red8[w][j] = acc[j];
        __syncthreads();
        if (t == 0) {
            float z[8];
            for (int j = 0; j < 8; j++) {
                float lg = p.br[j] + red8[0][j] + red8[1][j] + red8[2][j] + red8[3][j];
                z[j] = lg + gumbel_at(b * 8 + j);
            }
            int am = 0;
            float zm = z[0];
            for (int j = 1; j < 8; j++)
                if (z[j] > zm) { zm = z[j]; am = j; }
            float ssum = 0.f;
            for (int j = 0; j < 8; j++) ssum += expf(z[j] - zm);
            float s = 1.0f / ssum;
            p.sel_w[b] = (1.0f - s) + s;
            p.sel_r[b] = am;
        }
        __syncthreads();
    }
    grid.sync();

    // P8: regime-grouped K-split einsum (1024 tasks: n = task&127, r = task>>7)
    for (int task = blk; task < 1024; task += nblk) {
        int n = task & 127, r = task >> 7;
        if (t == 0) {
            int g = 0;
            for (int bb = 0; bb < 32; bb++)
                if (p.sel_r[bb] == r) loc[g++] = bb;
            s_gs = g;
        }
        __syncthreads();
        int gs = s_gs;
        if (gs != 0) {
            float* es = lds;  // [8][128]
            const float* pb = p.proto + ((size_t)r * 128 + n) * 128 * 192;
            for (int s0 = 0; s0 < gs; s0 += 8) {
                int np = gs - s0 < 8 ? gs - s0 : 8;
                {
                    int sb = t >> 5, h4 = t & 31;  // 256 threads = 8x32 float4
                    float4 v = make_float4(0.f, 0.f, 0.f, 0.f);
                    if (sb < np) {
                        int b = loc[s0 + sb];
                        v = ((const float4*)(p.e_st + ((size_t)b * 128 + n) * 128))[h4];
                    }
                    *(float4*)(&es[sb * 128 + h4 * 4]) = v;
                }
                __syncthreads();
                if (t < 192) {
                    float a0 = 0.f, a1 = 0.f, a2 = 0.f, a3 = 0.f;
                    float a4 = 0.f, a5 = 0.f, a6 = 0.f, a7 = 0.f;
#pragma unroll 8
                    for (int h = 0; h < 128; h++) {
                        float pv = pb[h * 192 + t];
                        a0 += es[0 * 128 + h] * pv; a1 += es[1 * 128 + h] * pv;
                        a2 += es[2 * 128 + h] * pv; a3 += es[3 * 128 + h] * pv;
                        a4 += es[4 * 128 + h] * pv; a5 += es[5 * 128 + h] * pv;
                        a6 += es[6 * 128 + h] * pv; a7 += es[7 * 128 + h] * pv;
                    }
                    float av[8] = {a0, a1, a2, a3, a4, a5, a6, a7};
#pragma unroll
                    for (int sb = 0; sb < 8; sb++) {
                        if (sb < np) {
                            int b = loc[s0 + sb];
                            p.part[((size_t)b * 128 + n) * 192 + t] = av[sb];
                        }
                    }
                }
                __syncthreads();
            }
        }
        __syncthreads();
    }
    grid.sync();

    // P9: finalize — reduce 128 n-partials, scale, softmax over 192 (32 tasks)
    for (int b = blk; b < 32; b += nblk) {
        float v = 0.f;
        if (t < 192) {
#pragma unroll 8
            for (int c = 0; c < 128; c++) v += p.part[((size_t)b * 128 + c) * 192 + t];
            v *= p.sel_w[b];
        }
        float mv = (t < 192) ? v : -3.402823466e+38f;
#pragma unroll
        for (int off = 32; off > 0; off >>= 1) mv = fmaxf(mv, __shfl_xor(mv, off, 64));
        if (ln == 0) red8[w][0] = mv;
        __syncthreads();
        float mx = fmaxf(fmaxf(red8[0][0], red8[1][0]), fmaxf(red8[2][0], red8[3][0]));
        float e = (t < 192) ? expf(v - mx) : 0.f;
        float se = e;
#pragma unroll
        for (int off = 32; off > 0; off >>= 1) se += __shfl_xor(se, off, 64);
        __syncthreads();
        if (ln == 0) red8[w][1] = se;
        __syncthreads();
        float s = red8[0][1] + red8[1][1] + red8[2][1] + red8[3][1];
        if (t < 192) p.out[(size_t)b * 192 + t] = e / s;
        __syncthreads();
    }
}

extern "C" void kernel_launch(void* const* d_in, const int* in_sizes, int n_in,
                              void* d_out, int out_size, void* d_ws, size_t ws_size,
                              hipStream_t stream) {
    float* ws = (float*)d_ws;
    size_t off = 0;
    MegaParams p;
    p.in_lt = (const float*)d_in[0];
    p.in_st = (const float*)d_in[1];
    p.Ws = (const float*)d_in[2];  p.bs = (const float*)d_in[3];
    p.Wt = (const float*)d_in[4];  p.bt = (const float*)d_in[5];
    p.Wh1 = (const float*)d_in[6]; p.bh1 = (const float*)d_in[7];
    p.Wl1 = (const float*)d_in[8]; p.bl1 = (const float*)d_in[9];
    p.Wh2 = (const float*)d_in[10]; p.bh2 = (const float*)d_in[11];
    p.Wl2 = (const float*)d_in[12]; p.bl2 = (const float*)d_in[13];
    p.Wh3 = (const float*)d_in[14]; p.bh3 = (const float*)d_in[15];
    p.Wl3 = (const float*)d_in[16]; p.bl3 = (const float*)d_in[17];
    p.Wr = (const float*)d_in[18]; p.br = (const float*)d_in[19];
    p.proto = (const float*)d_in[20];
    p.out = (float*)d_out;
    p.e_lt = ws + off; off += (size_t)32 * 512 * 128;
    p.e_st = ws + off; off += (size_t)32 * 128 * 128;
    p.O1T = ws + off; off += (size_t)128 * 16384;
    p.O2T = ws + off; off += (size_t)256 * 4096;
    p.O3T = ws + off; off += (size_t)128 * 8192;
    p.O4T = ws + off; off += (size_t)128 * 4096;
    p.O5T = ws + off; off += (size_t)128 * 4096;
    p.O6 = ws + off; off += (size_t)32 * 128 * 64;
    p.part = ws + off; off += (size_t)32 * 128 * 192;
    p.sel_w = ws + off; off += 32;
    p.sel_r = (int*)(ws + off); off += 32;

    void* kp[] = {&p};
    hipLaunchCooperativeKernel((const void*)mega, dim3(512), dim3(256), kp, 0, stream);
}

// Round 10
// 384.039 us; speedup vs baseline: 2.6050x; 2.6050x over previous
//
#include <hip/hip_runtime.h>
#include <math.h>

#define EPS 1e-5f

__device__ __forceinline__ float gelu_exact(float x) {
    return 0.5f * x * (1.0f + erff(x * 0.7071067811865476f));
}

// ---- block reductions for finalize (192 threads = 3 waves) ----
__device__ float block_sum(float v, float* red) {
    int lane = threadIdx.x & 63, wid = threadIdx.x >> 6;
#pragma unroll
    for (int off = 32; off > 0; off >>= 1) v += __shfl_down(v, off, 64);
    if (lane == 0) red[wid] = v;
    __syncthreads();
    int nw = ((int)blockDim.x + 63) >> 6;
    float s = red[0];
    for (int w = 1; w < nw; w++) s += red[w];
    __syncthreads();
    return s;
}

__device__ float block_max(float v, float* red) {
    int lane = threadIdx.x & 63, wid = threadIdx.x >> 6;
#pragma unroll
    for (int off = 32; off > 0; off >>= 1) v = fmaxf(v, __shfl_down(v, off, 64));
    if (lane == 0) red[wid] = v;
    __syncthreads();
    int nw = ((int)blockDim.x + 63) >> 6;
    float s = red[0];
    for (int w = 1; w < nw; w++) s = fmaxf(s, red[w]);
    __syncthreads();
    return s;
}

// ---- threefry2x32-20 (JAX PRNG), partitionable scheme (verified round 1) ----
__device__ void threefry2x32(unsigned k0, unsigned k1, unsigned x0, unsigned x1,
                             unsigned& o0, unsigned& o1) {
    unsigned ks[3] = {k0, k1, k0 ^ k1 ^ 0x1BD11BDAu};
    const unsigned rot[2][4] = {{13u, 15u, 26u, 6u}, {17u, 29u, 16u, 24u}};
    x0 += ks[0]; x1 += ks[1];
#pragma unroll
    for (int i = 0; i < 5; i++) {
#pragma unroll
        for (int j = 0; j < 4; j++) {
            unsigned r = rot[i & 1][j];
            x0 += x1;
            x1 = (x1 << r) | (x1 >> (32 - r));
            x1 ^= x0;
        }
        x0 += ks[(i + 1) % 3];
        x1 += ks[(i + 2) % 3] + (unsigned)(i + 1);
    }
    o0 = x0; o1 = x1;
}

__device__ float gumbel_at(int j) {
    unsigned o0, o1;
    threefry2x32(0u, 42u, 0u, (unsigned)j, o0, o1);
    unsigned bits = o0 ^ o1;
    float f = __uint_as_float((bits >> 9) | 0x3F800000u) - 1.0f;  // [0,1)
    float u = fmaxf(f + 1.17549435e-38f, 1.17549435e-38f);
    return -logf(-logf(u));
}

// ---- wave-level encode of one (b,l) row: returns (e[h=ln], e[h=ln+64]).
// Identical math to r7's passing encode_row_wave. ----
__device__ float2 encode_row(const float* __restrict__ xb, int L, int l, int ln,
                             const float* __restrict__ Ws, const float* __restrict__ bs,
                             const float* __restrict__ Wt, const float* __restrict__ bt) {
    float seas_v = 0.f, mm_v = 0.f;
    if (ln < 9) {
        float x0 = xb[ln];
        float s = 0.f;
#pragma unroll
        for (int j = -12; j <= 12; j++) {
            int lj = l + j;
            lj = lj < 0 ? 0 : (lj >= L ? L - 1 : lj);
            s += xb[(size_t)lj * 9 + ln];
        }
        float mm = (s - 25.f * x0) * (1.0f / 25.0f);
        mm_v = mm;
        seas_v = (xb[(size_t)l * 9 + ln] - x0) - mm;
    }
    int h1 = ln, h2 = ln + 64;
    float ys1 = bs[h1], ys2 = bs[h2], yt1 = bt[h1], yt2 = bt[h2];
#pragma unroll
    for (int c = 0; c < 9; c++) {
        float sc = __shfl(seas_v, c, 64);
        float mc = __shfl(mm_v, c, 64);
        ys1 += sc * Ws[c * 128 + h1]; ys2 += sc * Ws[c * 128 + h2];
        yt1 += mc * Wt[c * 128 + h1]; yt2 += mc * Wt[c * 128 + h2];
    }
    float sa = ys1 + ys2, sb = yt1 + yt2;
#pragma unroll
    for (int off = 32; off > 0; off >>= 1) {
        sa += __shfl_xor(sa, off, 64);
        sb += __shfl_xor(sb, off, 64);
    }
    float ms = sa * (1.0f / 128.0f), mt = sb * (1.0f / 128.0f);
    float d1 = ys1 - ms, d2 = ys2 - ms, f1 = yt1 - mt, f2 = yt2 - mt;
    float qa = d1 * d1 + d2 * d2, qb = f1 * f1 + f2 * f2;
#pragma unroll
    for (int off = 32; off > 0; off >>= 1) {
        qa += __shfl_xor(qa, off, 64);
        qb += __shfl_xor(qb, off, 64);
    }
    float is = rsqrtf(qa * (1.0f / 128.0f) + EPS);
    float it = rsqrtf(qb * (1.0f / 128.0f) + EPS);
    return make_float2(gelu_exact(d1 * is) + gelu_exact(f1 * it),
                       gelu_exact(d2 * is) + gelu_exact(f2 * it));
}

// ---- h1 with fused long-term encode (blocks <1024) + short-term encode
// (blocks >=1024). h1 body = r6-proven lbr_wave<128,128,2,true> config. ----
__global__ __launch_bounds__(256) void h1_enc(
    const float* __restrict__ in_lt, const float* __restrict__ in_st,
    const float* __restrict__ Ws, const float* __restrict__ bs,
    const float* __restrict__ Wt, const float* __restrict__ bt,
    const float* __restrict__ W, const float* __restrict__ bias,
    float* __restrict__ O1T, float* __restrict__ e_st) {
    const int t = threadIdx.x, w = t >> 6, ln = t & 63;
    const int blk = blockIdx.x;
    if (blk < 1024) {
        // K=128, N=128, WR=2 -> CG=32, SG=2, RW=4, MT=16
        __shared__ float lds[2112];  // max(stage 2048, tile 16*132=2112)
        const int sg = ln >> 5;
        const int n0 = (ln & 31) * 4;
        const int r0b = blk * 16, r0w = r0b + w * 4;
        float* As = lds + w * 512;
        for (int rr = 0; rr < 4; rr++) {
            int row = r0w + rr, bb = row >> 9, l = row & 511;
            float2 o = encode_row(in_lt + (size_t)bb * 4608, 512, l, ln, Ws, bs, Wt, bt);
            As[rr * 128 + ln] = o.x;
            As[rr * 128 + ln + 64] = o.y;
        }
        float4 acc[2];
        {
            float4 bv = *(const float4*)(bias + n0);
            acc[0] = bv; acc[1] = bv;
        }
        const float* ap = As + (sg * 2) * 128;
        const float* wp = W + n0;
#pragma unroll 2
        for (int k = 0; k < 128; k += 4) {
            float4 w0 = *(const float4*)(wp);
            float4 w1 = *(const float4*)(wp + 128);
            float4 w2 = *(const float4*)(wp + 256);
            float4 w3 = *(const float4*)(wp + 384);
            wp += 512;
#pragma unroll
            for (int j = 0; j < 2; j++) {
                float4 a4 = *(const float4*)(ap + j * 128 + k);
                acc[j].x += a4.x * w0.x; acc[j].y += a4.x * w0.y;
                acc[j].z += a4.x * w0.z; acc[j].w += a4.x * w0.w;
                acc[j].x += a4.y * w1.x; acc[j].y += a4.y * w1.y;
                acc[j].z += a4.y * w1.z; acc[j].w += a4.y * w1.w;
                acc[j].x += a4.z * w2.x; acc[j].y += a4.z * w2.y;
                acc[j].z += a4.z * w2.z; acc[j].w += a4.z * w2.w;
                acc[j].x += a4.w * w3.x; acc[j].y += a4.w * w3.y;
                acc[j].z += a4.w * w3.z; acc[j].w += a4.w * w3.w;
            }
        }
        float4 res[2];
#pragma unroll
        for (int j = 0; j < 2; j++) {
            float s = acc[j].x + acc[j].y + acc[j].z + acc[j].w;
#pragma unroll
            for (int off = 16; off > 0; off >>= 1) s += __shfl_xor(s, off, 64);
            float m = s * (1.0f / 128.0f);
            float dx = acc[j].x - m, dy = acc[j].y - m, dz = acc[j].z - m, dw = acc[j].w - m;
            float q = dx * dx + dy * dy + dz * dz + dw * dw;
#pragma unroll
            for (int off = 16; off > 0; off >>= 1) q += __shfl_xor(q, off, 64);
            float inv = rsqrtf(q * (1.0f / 128.0f) + EPS);
            res[j].x = gelu_exact(dx * inv);
            res[j].y = gelu_exact(dy * inv);
            res[j].z = gelu_exact(dz * inv);
            res[j].w = gelu_exact(dw * inv);
        }
        __syncthreads();
#pragma unroll
        for (int j = 0; j < 2; j++) {
            int rl = w * 4 + sg * 2 + j;
            *(float4*)(lds + rl * 132 + n0) = res[j];
        }
        __syncthreads();
        float* ob = O1T + r0b;
        for (int e2 = t; e2 < 16 * 128; e2 += 256) {
            int r = e2 & 15, n = e2 >> 4;
            ob[(size_t)n * 16384 + r] = lds[r * 132 + n];
        }
    } else {
        for (int row = (blk - 1024) * 4 + w; row < 4096; row += 256) {
            int b = row >> 7, l = row & 127;
            float2 o = encode_row(in_st + (size_t)b * 1152, 128, l, ln, Ws, bs, Wt, bt);
            float* eb = e_st + (size_t)row * 128;
            eb[ln] = o.x;
            eb[ln + 64] = o.y;
        }
    }
}

// ---- wave-autonomous Linear -> InstanceNorm -> GELU (r6-proven, verbatim) ----
template <int K, int N, int WR, bool TRANS>
__global__ __launch_bounds__(256) void lbr_wave(
    const float* __restrict__ A, int S, int ABOFF,
    const float* __restrict__ W, const float* __restrict__ bias,
    float* __restrict__ out, int OROWS, int OBOFF) {
    constexpr int CG = N / 4;
    constexpr int SG = 64 / CG;
    constexpr int RW = SG * WR;
    constexpr int MT = 4 * RW;
    constexpr int LOG2MT = (MT == 8) ? 3 : ((MT == 16) ? 4 : 5);
    constexpr int STAGE = 4 * RW * K;
    constexpr int TILE = TRANS ? MT * (N + 4) : 0;
    constexpr int LSZ = STAGE > TILE ? STAGE : TILE;
    __shared__ float lds[LSZ];
    const int t = threadIdx.x;
    const int w = t >> 6, ln = t & 63;
    const int sg = ln / CG;
    const int n0 = (ln % CG) * 4;
    const int b = blockIdx.y;
    const int r0b = blockIdx.x * MT;
    const int r0w = r0b + w * RW;
    float* As = lds + w * RW * K;
    const float* Ab = A + (size_t)b * ABOFF;
    for (int idx = ln; idx < RW * (K / 4); idx += 64) {
        int rr = idx / (K / 4), kk = idx % (K / 4);
        float4 v = *(const float4*)(Ab + (size_t)(r0w + rr) * S + kk * 4);
        *(float4*)(As + rr * K + kk * 4) = v;
    }
    float4 acc[WR];
    {
        float4 bv = *(const float4*)(bias + n0);
#pragma unroll
        for (int j = 0; j < WR; j++) acc[j] = bv;
    }
    const float* ap = As + (sg * WR) * K;
    const float* wp = W + n0;
#pragma unroll 2
    for (int k = 0; k < K; k += 4) {
        float4 w0 = *(const float4*)(wp);
        float4 w1 = *(const float4*)(wp + N);
        float4 w2 = *(const float4*)(wp + 2 * N);
        float4 w3 = *(const float4*)(wp + 3 * N);
        wp += 4 * N;
#pragma unroll
        for (int j = 0; j < WR; j++) {
            float4 a4 = *(const float4*)(ap + j * K + k);
            acc[j].x += a4.x * w0.x; acc[j].y += a4.x * w0.y;
            acc[j].z += a4.x * w0.z; acc[j].w += a4.x * w0.w;
            acc[j].x += a4.y * w1.x; acc[j].y += a4.y * w1.y;
            acc[j].z += a4.y * w1.z; acc[j].w += a4.y * w1.w;
            acc[j].x += a4.z * w2.x; acc[j].y += a4.z * w2.y;
            acc[j].z += a4.z * w2.z; acc[j].w += a4.z * w2.w;
            acc[j].x += a4.w * w3.x; acc[j].y += a4.w * w3.y;
            acc[j].z += a4.w * w3.z; acc[j].w += a4.w * w3.w;
        }
    }
    float4 res[WR];
#pragma unroll
    for (int j = 0; j < WR; j++) {
        float s = acc[j].x + acc[j].y + acc[j].z + acc[j].w;
#pragma unroll
        for (int off = CG / 2; off > 0; off >>= 1) s += __shfl_xor(s, off, 64);
        float m = s * (1.0f / (float)N);
        float dx = acc[j].x - m, dy = acc[j].y - m, dz = acc[j].z - m, dw = acc[j].w - m;
        float q = dx * dx + dy * dy + dz * dz + dw * dw;
#pragma unroll
        for (int off = CG / 2; off > 0; off >>= 1) q += __shfl_xor(q, off, 64);
        float inv = rsqrtf(q * (1.0f / (float)N) + EPS);
        res[j].x = gelu_exact(dx * inv);
        res[j].y = gelu_exact(dy * inv);
        res[j].z = gelu_exact(dz * inv);
        res[j].w = gelu_exact(dw * inv);
    }
    if constexpr (TRANS) {
        __syncthreads();
#pragma unroll
        for (int j = 0; j < WR; j++) {
            int rl = w * RW + sg * WR + j;
            *(float4*)(lds + rl * (N + 4) + n0) = res[j];
        }
        __syncthreads();
        float* ob = out + (size_t)b * OBOFF + r0b;
        for (int e = t; e < MT * N; e += 256) {
            int r = e & (MT - 1), n = e >> LOG2MT;
            ob[(size_t)n * OROWS + r] = lds[r * (N + 4) + n];
        }
    } else {
        float* ob = out + (size_t)b * OBOFF;
#pragma unroll
        for (int j = 0; j < WR; j++) {
            int row = r0w + sg * WR + j;
            *(float4*)(ob + (size_t)row * N + n0) = res[j];
        }
    }
}

// ---- fused logits + gumbel-softmax(hard) selection (r6-proven, verbatim) ----
__global__ __launch_bounds__(256) void logits_select(
    const float* __restrict__ O6, const float* __restrict__ Wr,
    const float* __restrict__ br, float* __restrict__ sel_w, int* __restrict__ sel_r) {
    int b = blockIdx.x, t = threadIdx.x;
    __shared__ float sO6[128 * 68];
    __shared__ float red[4][8];
    const float4* ob4 = (const float4*)(O6 + (size_t)b * 8192);
    for (int i4 = t; i4 < 2048; i4 += 256) {
        float4 v = ob4[i4];
        int p = i4 * 4;
        int h = p >> 6, l4 = p & 63;
        *(float4*)(&sO6[h * 68 + l4]) = v;
    }
    __syncthreads();
    float acc[8] = {0, 0, 0, 0, 0, 0, 0, 0};
#pragma unroll 4
    for (int q = 0; q < 32; q++) {
        int i = q * 256 + t;
        int l4 = i >> 7, h = i & 127;
        float v = sO6[h * 68 + l4];
        const float4* wr = (const float4*)(Wr + (size_t)i * 8);
        float4 w0 = wr[0], w1 = wr[1];
        acc[0] += v * w0.x; acc[1] += v * w0.y; acc[2] += v * w0.z; acc[3] += v * w0.w;
        acc[4] += v * w1.x; acc[5] += v * w1.y; acc[6] += v * w1.z; acc[7] += v * w1.w;
    }
#pragma unroll
    for (int j = 0; j < 8; j++)
#pragma unroll
        for (int off = 32; off > 0; off >>= 1) acc[j] += __shfl_xor(acc[j], off, 64);
    int lane = t & 63, wid = t >> 6;
    if (lane == 0)
        for (int j = 0; j < 8; j++) red[wid][j] = acc[j];
    __syncthreads();
    if (t == 0) {
        float z[8];
        for (int j = 0; j < 8; j++) {
            float lg = br[j] + red[0][j] + red[1][j] + red[2][j] + red[3][j];
            z[j] = lg + gumbel_at(b * 8 + j);
        }
        int am = 0;
        float zm = z[0];
        for (int j = 1; j < 8; j++)
            if (z[j] > zm) { zm = z[j]; am = j; }
        float ssum = 0.f;
        for (int j = 0; j < 8; j++) ssum += expf(z[j] - zm);
        float s = 1.0f / ssum;
        sel_w[b] = (1.0f - s) + s;
        sel_r[b] = am;
    }
}

// ---- regime-grouped, K-split einsum (r6-proven, verbatim) ----
__global__ void einsum_nsplit(const float* __restrict__ e_st, const float* __restrict__ proto,
                              const int* __restrict__ sel_r, float* __restrict__ part) {
    int n = blockIdx.x, r = blockIdx.y, t = threadIdx.x;
    __shared__ int loc[32];
    __shared__ int s_gs;
    if (t == 0) {
        int g = 0;
        for (int bb = 0; bb < 32; bb++)
            if (sel_r[bb] == r) loc[g++] = bb;
        s_gs = g;
    }
    __syncthreads();
    int gs = s_gs;
    if (gs == 0) return;
    __shared__ float es[8][128];
    const float* pb = proto + ((size_t)r * 128 + n) * 128 * 192;
    for (int s0 = 0; s0 < gs; s0 += 8) {
        int np = gs - s0 < 8 ? gs - s0 : 8;
        __syncthreads();
        for (int i4 = t; i4 < 256; i4 += 192) {
            int sb = i4 >> 5, h4 = i4 & 31;
            float4 v = make_float4(0.f, 0.f, 0.f, 0.f);
            if (sb < np) {
                int b = loc[s0 + sb];
                v = ((const float4*)(e_st + ((size_t)b * 128 + n) * 128))[h4];
            }
            *(float4*)(&es[sb][h4 * 4]) = v;
        }
        __syncthreads();
        float a0 = 0.f, a1 = 0.f, a2 = 0.f, a3 = 0.f;
        float a4 = 0.f, a5 = 0.f, a6 = 0.f, a7 = 0.f;
#pragma unroll 8
        for (int h = 0; h < 128; h++) {
            float p = pb[h * 192 + t];
            a0 += es[0][h] * p; a1 += es[1][h] * p;
            a2 += es[2][h] * p; a3 += es[3][h] * p;
            a4 += es[4][h] * p; a5 += es[5][h] * p;
            a6 += es[6][h] * p; a7 += es[7][h] * p;
        }
        float av[8] = {a0, a1, a2, a3, a4, a5, a6, a7};
#pragma unroll
        for (int sb = 0; sb < 8; sb++) {
            if (sb < np) {
                int b = loc[s0 + sb];
                part[((size_t)b * 128 + n) * 192 + t] = av[sb];
            }
        }
    }
}

// ---- reduce 128 n-partials, scale, softmax (r6-proven, verbatim) ----
__global__ void finalize_kernel(const float* __restrict__ part, const float* __restrict__ sel_w,
                                float* __restrict__ out) {
    int b = blockIdx.x, t = threadIdx.x;
    __shared__ float red[4];
    float v = 0.f;
#pragma unroll 8
    for (int c = 0; c < 128; c++) v += part[((size_t)b * 128 + c) * 192 + t];
    v *= sel_w[b];
    float mx = block_max(v, red);
    float e = expf(v - mx);
    float s = block_sum(e, red);
    out[(size_t)b * 192 + t] = e / s;
}

extern "C" void kernel_launch(void* const* d_in, const int* in_sizes, int n_in,
                              void* d_out, int out_size, void* d_ws, size_t ws_size,
                              hipStream_t stream) {
    const float* in_lt = (const float*)d_in[0];
    const float* in_st = (const float*)d_in[1];
    const float* Ws  = (const float*)d_in[2];  const float* bs  = (const float*)d_in[3];
    const float* Wt  = (const float*)d_in[4];  const float* bt  = (const float*)d_in[5];
    const float* Wh1 = (const float*)d_in[6];  const float* bh1 = (const float*)d_in[7];
    const float* Wl1 = (const float*)d_in[8];  const float* bl1 = (const float*)d_in[9];
    const float* Wh2 = (const float*)d_in[10]; const float* bh2 = (const float*)d_in[11];
    const float* Wl2 = (const float*)d_in[12]; const float* bl2 = (const float*)d_in[13];
    const float* Wh3 = (const float*)d_in[14]; const float* bh3 = (const float*)d_in[15];
    const float* Wl3 = (const float*)d_in[16]; const float* bl3 = (const float*)d_in[17];
    const float* Wr  = (const float*)d_in[18]; const float* br  = (const float*)d_in[19];
    const float* proto = (const float*)d_in[20];
    float* out = (float*)d_out;

    float* ws = (float*)d_ws;
    size_t off = 0;
    float* e_st = ws + off; off += (size_t)32 * 128 * 128;   // [b,n][h]
    float* O1T = ws + off; off += (size_t)128 * 16384;       // [h][(b,l)]
    float* O2T = ws + off; off += (size_t)256 * 4096;        // [l2][(b,h)]
    float* O3T = ws + off; off += (size_t)128 * 8192;        // [h][(b,l2)]
    float* O4T = ws + off; off += (size_t)128 * 4096;        // [l3][(b,h)]
    float* O5T = ws + off; off += (size_t)128 * 4096;        // [h][(b,l3)]
    float* O6 = ws + off; off += (size_t)32 * 128 * 64;      // [b][h][l4]
    float* part = ws + off; off += (size_t)32 * 128 * 192;
    float* sel_w = ws + off; off += 32;
    int* sel_r = (int*)(ws + off); off += 32;

    // h1 (with fused lt-encode) + st-encode in one launch
    h1_enc<<<1088, 256, 0, stream>>>(in_lt, in_st, Ws, bs, Wt, bt, Wh1, bh1, O1T, e_st);
    // l1: rows=h(128)/b, K=512, N=256 -> O2T[l2][4096]
    lbr_wave<512, 256, 2, true><<<dim3(16, 32), 256, 0, stream>>>(
        O1T, 16384, 512, Wl1, bl1, O2T, 4096, 128);
    // h2: rows=l2(256)/b, K=128, N=128 -> O3T[h][8192]
    lbr_wave<128, 128, 2, true><<<dim3(16, 32), 256, 0, stream>>>(
        O2T, 4096, 128, Wh2, bh2, O3T, 8192, 256);
    // l2: rows=h(128)/b, K=256, N=128 -> O4T[l3][4096]
    lbr_wave<256, 128, 1, true><<<dim3(16, 32), 256, 0, stream>>>(
        O3T, 8192, 256, Wl2, bl2, O4T, 4096, 128);
    // h3: rows=l3(128)/b, K=128, N=128 -> O5T[h][4096]
    lbr_wave<128, 128, 1, true><<<dim3(16, 32), 256, 0, stream>>>(
        O4T, 4096, 128, Wh3, bh3, O5T, 4096, 128);
    // l3: rows=h(128)/b, K=128, N=64 -> O6 natural [b][h][l4]
    lbr_wave<128, 64, 1, false><<<dim3(8, 32), 256, 0, stream>>>(
        O5T, 4096, 128, Wl3, bl3, O6, 0, 8192);
    logits_select<<<32, 256, 0, stream>>>(O6, Wr, br, sel_w, sel_r);
    einsum_nsplit<<<dim3(128, 8), 192, 0, stream>>>(e_st, proto, sel_r, part);
    finalize_kernel<<<32, 192, 0, stream>>>(part, sel_w, out);
}